// Round 1
// 6518.708 us; speedup vs baseline: 2.0032x; 2.0032x over previous
//
#include <hip/hip_runtime.h>

#define NN 100000
#define EE 400000
#define DD 300
#define KP 320      // K and N padded to 320 for MFMA (zeros in pads)
#define LDA 328     // LDS row stride (bf16 elems): 16B-aligned rows, bank-spread

typedef __bf16 bf16x8 __attribute__((ext_vector_type(8)));
typedef __bf16 bf16x4 __attribute__((ext_vector_type(4)));
typedef float  floatx4 __attribute__((ext_vector_type(4)));

struct WPtrs { const float* w[27]; };

// ---- weight prep: W[k][n] f32 [300x300] -> Wt[n][k] bf16 [320x320], pads zero ----
__global__ void k_prep_weights(WPtrs p, __bf16* __restrict__ wt) {
  __shared__ float tile[64][65];
  const float* W = p.w[blockIdx.z];
  __bf16* out = wt + (size_t)blockIdx.z * (KP * KP);
  const int kb = blockIdx.x * 64, nb = blockIdx.y * 64;
  for (int i = threadIdx.x; i < 64 * 64; i += 256) {
    int tx = i & 63, ty = i >> 6;
    int k = kb + ty, n = nb + tx;
    tile[ty][tx] = (k < DD && n < DD) ? W[k * DD + n] : 0.f;
  }
  __syncthreads();
  for (int i = threadIdx.x; i < 64 * 64; i += 256) {
    int tx = i & 63, ty = i >> 6;
    out[(size_t)(nb + ty) * KP + (kb + tx)] = (__bf16)tile[tx][ty];
  }
}

// ---- stage 64 rows of f32 [M x 300] into LDS bf16 [64 x LDA], K-pad zeroed ----
// rows >= limit are zero-filled (node kernels: N not a multiple of 64)
__device__ __forceinline__ void stage_A64(const float* __restrict__ A, int m0,
                                          int limit, __bf16* lds) {
  for (int i = threadIdx.x; i < 64 * 75; i += 256) {
    int r = i / 75, c4 = (i % 75) * 4;
    bf16x4 b;
    if (m0 + r < limit) {
      float4 v = *(const float4*)(A + (size_t)(m0 + r) * DD + c4);
      b[0] = (__bf16)v.x; b[1] = (__bf16)v.y; b[2] = (__bf16)v.z; b[3] = (__bf16)v.w;
    } else {
      b[0] = (__bf16)0.f; b[1] = (__bf16)0.f; b[2] = (__bf16)0.f; b[3] = (__bf16)0.f;
    }
    *(bf16x4*)(lds + r * LDA + c4) = b;
  }
  for (int i = threadIdx.x; i < 64 * (LDA - DD); i += 256) {
    int r = i / (LDA - DD), c = DD + i % (LDA - DD);
    lds[r * LDA + c] = (__bf16)0.f;
  }
}

// ---- one GEMM pass: C[64x320] = A_lds[64x320] @ Wt^T ----
// wave owns ALL 64 rows x 80 cols: acc[mi][t], mi = 16-row band, t = 16-col band.
// A frag: A[m = mi*16 + (lane&15)][k = quad*8 + j]
// B frag: B[k = quad*8 + j][n = lane&15] = Wt[n][k] contiguous.
__device__ __forceinline__ void gemm64(const __bf16* Alds,
                                       const __bf16* __restrict__ Wt,
                                       int colbase, int quad, int nloc,
                                       floatx4 acc[4][5]) {
#pragma unroll 2
  for (int ks = 0; ks < 10; ++ks) {
    const int k0 = ks * 32 + quad * 8;
    bf16x8 b[5];
#pragma unroll
    for (int t = 0; t < 5; ++t)
      b[t] = *(const bf16x8*)(Wt + (size_t)(colbase + t * 16 + nloc) * KP + k0);
#pragma unroll
    for (int mi = 0; mi < 4; ++mi) {
      bf16x8 a = *(const bf16x8*)(Alds + (mi * 16 + nloc) * LDA + k0);
#pragma unroll
      for (int t = 0; t < 5; ++t)
        acc[mi][t] = __builtin_amdgcn_mfma_f32_16x16x32_bf16(a, b[t], acc[mi][t], 0, 0, 0);
    }
  }
}

#define WAVE64_SETUP                                               \
  const int lane = threadIdx.x & 63, wave = threadIdx.x >> 6;      \
  const int colbase = wave * 80;                                   \
  const int quad = lane >> 4, nloc = lane & 15;                    \
  (void)lane;

#define ZERO_ACC                                                   \
  _Pragma("unroll") for (int mi = 0; mi < 4; ++mi)                 \
  _Pragma("unroll") for (int t = 0; t < 5; ++t)                    \
    acc[mi][t] = (floatx4){0.f, 0.f, 0.f, 0.f};

// ---- xin = x @ W_in, xout = x @ W_out  (bf16 out, stride KP, pads become 0) ----
__global__ __launch_bounds__(256, 3) void k_node_proj(
    const float* __restrict__ x,
    const __bf16* __restrict__ WtA, const __bf16* __restrict__ WtB,
    __bf16* __restrict__ outA, __bf16* __restrict__ outB) {
  __shared__ __attribute__((aligned(16))) __bf16 Alds[64 * LDA];
  const int m0 = blockIdx.x * 64;
  stage_A64(x, m0, NN, Alds);
  __syncthreads();
  WAVE64_SETUP
  floatx4 acc[4][5];
  ZERO_ACC
  gemm64(Alds, WtA, colbase, quad, nloc, acc);
#pragma unroll
  for (int mi = 0; mi < 4; ++mi)
#pragma unroll
    for (int t = 0; t < 5; ++t) {
      const int n = colbase + t * 16 + nloc;
#pragma unroll
      for (int r = 0; r < 4; ++r) {
        const int row = mi * 16 + quad * 4 + r;
        if (m0 + row < NN)
          outA[(size_t)(m0 + row) * KP + n] = (__bf16)acc[mi][t][r];
      }
    }
  ZERO_ACC
  gemm64(Alds, WtB, colbase, quad, nloc, acc);
#pragma unroll
  for (int mi = 0; mi < 4; ++mi)
#pragma unroll
    for (int t = 0; t < 5; ++t) {
      const int n = colbase + t * 16 + nloc;
#pragma unroll
      for (int r = 0; r < 4; ++r) {
        const int row = mi * 16 + quad * 4 + r;
        if (m0 + row < NN)
          outB[(size_t)(m0 + row) * KP + n] = (__bf16)acc[mi][t][r];
      }
    }
}

// ---- fused edge path: EdgeModel (3 GEMMs, gathers, residual) + NodeModel edge MLP
//      (2 GEMMs) + atomic scatter into agg. Single LDS buffer ping-pong:
//      gemm reads Alds -> barrier -> overwrite Alds with next H -> barrier. ----
__global__ __launch_bounds__(256, 3) void k_edge_all(
    float* __restrict__ ea, const int* __restrict__ eidx,
    const __bf16* __restrict__ xin_b, const __bf16* __restrict__ xout_b,
    const __bf16* __restrict__ Wt_e, const float* __restrict__ b_e,
    const __bf16* __restrict__ Wt_1, const float* __restrict__ b_1,
    const __bf16* __restrict__ Wt_2, const float* __restrict__ b_2,
    const __bf16* __restrict__ Wt_a, const float* __restrict__ b_a,
    const __bf16* __restrict__ Wt_b, const float* __restrict__ b_b,
    const float* __restrict__ eps_p, float* __restrict__ agg) {
  __shared__ __attribute__((aligned(16))) __bf16 Alds[64 * LDA];
  __shared__ int ridx[64], cidx[64];
  const int m0 = blockIdx.x * 64;
  stage_A64(ea, m0, EE, Alds);
  if (threadIdx.x < 64) {
    ridx[threadIdx.x] = eidx[m0 + threadIdx.x];
    cidx[threadIdx.x] = eidx[EE + m0 + threadIdx.x];
  }
  __syncthreads();
  WAVE64_SETUP
  floatx4 acc[4][5];

  // --- G1: f_ij = ea @ W_edge ---
  ZERO_ACC
  gemm64(Alds, Wt_e, colbase, quad, nloc, acc);
  __syncthreads();   // all waves done reading Alds
  // H0 = relu(f_ij + b_edge + xin[row] + xout[col]); pads stay 0
#pragma unroll
  for (int mi = 0; mi < 4; ++mi)
#pragma unroll
    for (int t = 0; t < 5; ++t) {
      const int n = colbase + t * 16 + nloc;
      const float bias = (n < DD) ? b_e[n] : 0.f;
#pragma unroll
      for (int r = 0; r < 4; ++r) {
        const int row = mi * 16 + quad * 4 + r;
        const float xi = (float)xin_b[(size_t)ridx[row] * KP + n];
        const float xj = (float)xout_b[(size_t)cidx[row] * KP + n];
        Alds[row * LDA + n] = (__bf16)fmaxf(acc[mi][t][r] + bias + xi + xj, 0.f);
      }
    }
  __syncthreads();

  // --- G2: H1 = relu(H0 @ W_em1 + b_em1) ---
  ZERO_ACC
  gemm64(Alds, Wt_1, colbase, quad, nloc, acc);
  __syncthreads();
#pragma unroll
  for (int mi = 0; mi < 4; ++mi)
#pragma unroll
    for (int t = 0; t < 5; ++t) {
      const int n = colbase + t * 16 + nloc;
      const float bias = (n < DD) ? b_1[n] : 0.f;
#pragma unroll
      for (int r = 0; r < 4; ++r) {
        const int row = mi * 16 + quad * 4 + r;
        Alds[row * LDA + n] = (__bf16)fmaxf(acc[mi][t][r] + bias, 0.f);
      }
    }
  __syncthreads();

  // --- G3: ea_new = (1+eps)*ea + H1 @ W_em2 + b_em2 ; write global fp32, keep bf16 in LDS ---
  ZERO_ACC
  gemm64(Alds, Wt_2, colbase, quad, nloc, acc);
  __syncthreads();
  const float ep = 1.f + eps_p[0];
#pragma unroll
  for (int mi = 0; mi < 4; ++mi)
#pragma unroll
    for (int t = 0; t < 5; ++t) {
      const int n = colbase + t * 16 + nloc;
#pragma unroll
      for (int r = 0; r < 4; ++r) {
        const int row = mi * 16 + quad * 4 + r;
        float v = 0.f;
        if (n < DD) {
          const size_t off = (size_t)(m0 + row) * DD + n;
          v = ep * ea[off] + acc[mi][t][r] + b_2[n];   // fp32 residual, rows owned by block
          ea[off] = v;
        }
        Alds[row * LDA + n] = (__bf16)v;
      }
    }
  __syncthreads();

  // --- G4: H2 = relu(ea_new @ W_n1a + b_n1a) ---
  ZERO_ACC
  gemm64(Alds, Wt_a, colbase, quad, nloc, acc);
  __syncthreads();
#pragma unroll
  for (int mi = 0; mi < 4; ++mi)
#pragma unroll
    for (int t = 0; t < 5; ++t) {
      const int n = colbase + t * 16 + nloc;
      const float bias = (n < DD) ? b_a[n] : 0.f;
#pragma unroll
      for (int r = 0; r < 4; ++r) {
        const int row = mi * 16 + quad * 4 + r;
        Alds[row * LDA + n] = (__bf16)fmaxf(acc[mi][t][r] + bias, 0.f);
      }
    }
  __syncthreads();

  // --- G5: m = H2 @ W_n1b + b_n1b ; scatter-add into agg[col] ---
  ZERO_ACC
  gemm64(Alds, Wt_b, colbase, quad, nloc, acc);
#pragma unroll
  for (int mi = 0; mi < 4; ++mi)
#pragma unroll
    for (int t = 0; t < 5; ++t) {
      const int n = colbase + t * 16 + nloc;
      if (n >= DD) continue;
      const float bias = b_b[n];
#pragma unroll
      for (int r = 0; r < 4; ++r) {
        const int row = mi * 16 + quad * 4 + r;
        unsafeAtomicAdd(&agg[(size_t)cidx[row] * DD + n], acc[mi][t][r] + bias);
      }
    }
}

// ---- upd = MLP(agg); x = (1+eps)*x + upd ----
__global__ __launch_bounds__(256, 3) void k_node_upd(
    const float* __restrict__ agg,
    const __bf16* __restrict__ Wt_a, const float* __restrict__ b_a,
    const __bf16* __restrict__ Wt_b, const float* __restrict__ b_b,
    float* __restrict__ x, const float* __restrict__ eps_p) {
  __shared__ __attribute__((aligned(16))) __bf16 Alds[64 * LDA];
  const int m0 = blockIdx.x * 64;
  stage_A64(agg, m0, NN, Alds);
  __syncthreads();
  WAVE64_SETUP
  floatx4 acc[4][5];
  ZERO_ACC
  gemm64(Alds, Wt_a, colbase, quad, nloc, acc);
  __syncthreads();
#pragma unroll
  for (int mi = 0; mi < 4; ++mi)
#pragma unroll
    for (int t = 0; t < 5; ++t) {
      const int n = colbase + t * 16 + nloc;
      const float bias = (n < DD) ? b_a[n] : 0.f;
#pragma unroll
      for (int r = 0; r < 4; ++r) {
        const int row = mi * 16 + quad * 4 + r;
        Alds[row * LDA + n] = (__bf16)fmaxf(acc[mi][t][r] + bias, 0.f);
      }
    }
  __syncthreads();
  ZERO_ACC
  gemm64(Alds, Wt_b, colbase, quad, nloc, acc);
  const float ep = 1.f + eps_p[0];
#pragma unroll
  for (int mi = 0; mi < 4; ++mi)
#pragma unroll
    for (int t = 0; t < 5; ++t) {
      const int n = colbase + t * 16 + nloc;
      if (n >= DD) continue;
      const float bias = b_b[n];
#pragma unroll
      for (int r = 0; r < 4; ++r) {
        const int row = mi * 16 + quad * 4 + r;
        if (m0 + row < NN) {
          const size_t off = (size_t)(m0 + row) * DD + n;
          x[off] = ep * x[off] + acc[mi][t][r] + bias;
        }
      }
    }
}

extern "C" void kernel_launch(void* const* d_in, const int* in_sizes, int n_in,
                              void* d_out, int out_size, void* d_ws, size_t ws_size,
                              hipStream_t stream) {
  const float* x_in   = (const float*)d_in[0];
  const float* ea_in  = (const float*)d_in[1];
  const int*   eidx   = (const int*)d_in[2];
  const float* W_edge = (const float*)d_in[3];
  const float* b_edge = (const float*)d_in[4];
  const float* W_in   = (const float*)d_in[5];
  const float* W_out  = (const float*)d_in[6];
  const float* W_em1  = (const float*)d_in[7];
  const float* b_em1  = (const float*)d_in[8];
  const float* W_em2  = (const float*)d_in[9];
  const float* b_em2  = (const float*)d_in[10];
  const float* W_n1a  = (const float*)d_in[11];
  const float* b_n1a  = (const float*)d_in[12];
  const float* W_n1b  = (const float*)d_in[13];
  const float* b_n1b  = (const float*)d_in[14];
  const float* W_n2a  = (const float*)d_in[15];
  const float* b_n2a  = (const float*)d_in[16];
  const float* W_n2b  = (const float*)d_in[17];
  const float* b_n2b  = (const float*)d_in[18];
  const float* e_eps  = (const float*)d_in[19];
  const float* n_eps  = (const float*)d_in[20];

  float* x  = (float*)d_out;                   // fp32 master x  [N x 300]
  float* ea = (float*)d_out + (size_t)NN * DD; // fp32 master edge_attr [E x 300]

  char* ws = (char*)d_ws;
  __bf16* Wt     = (__bf16*)ws;                               // 27 * 320*320 * 2 = 5,529,600 B
  __bf16* xin_b  = (__bf16*)(ws + 5529600);                   // N*320*2 = 64,000,000 B
  __bf16* xout_b = (__bf16*)(ws + 5529600 + 64000000);        // 64,000,000 B
  float*  agg    = (float*)(ws + 5529600 + 128000000);        // N*300*4 = 120,000,000 B

  hipMemcpyAsync(x,  x_in,  (size_t)NN * DD * 4, hipMemcpyDeviceToDevice, stream);
  hipMemcpyAsync(ea, ea_in, (size_t)EE * DD * 4, hipMemcpyDeviceToDevice, stream);

  WPtrs wp;
  for (int l = 0; l < 3; ++l) {
    const size_t o = (size_t)l * DD * DD;
    wp.w[l*9 + 0] = W_edge + o; wp.w[l*9 + 1] = W_in  + o; wp.w[l*9 + 2] = W_out + o;
    wp.w[l*9 + 3] = W_em1 + o;  wp.w[l*9 + 4] = W_em2 + o;
    wp.w[l*9 + 5] = W_n1a + o;  wp.w[l*9 + 6] = W_n1b + o;
    wp.w[l*9 + 7] = W_n2a + o;  wp.w[l*9 + 8] = W_n2b + o;
  }
  k_prep_weights<<<dim3(5, 5, 27), 256, 0, stream>>>(wp, Wt);

  const int nblk_node = (NN + 63) / 64;   // 1563, tail rows guarded
  const int nblk_edge = EE / 64;          // 6250, exact

  for (int l = 0; l < 3; ++l) {
    const __bf16* wt = Wt + (size_t)l * 9 * KP * KP;
    const size_t bo = (size_t)l * DD;
    k_node_proj<<<nblk_node, 256, 0, stream>>>(x, wt + 1 * KP * KP, wt + 2 * KP * KP,
                                               xin_b, xout_b);
    hipMemsetAsync(agg, 0, (size_t)NN * DD * 4, stream);
    k_edge_all<<<nblk_edge, 256, 0, stream>>>(ea, eidx, xin_b, xout_b,
        wt + 0 * KP * KP, b_edge + bo,
        wt + 3 * KP * KP, b_em1 + bo,
        wt + 4 * KP * KP, b_em2 + bo,
        wt + 5 * KP * KP, b_n1a + bo,
        wt + 6 * KP * KP, b_n1b + bo,
        e_eps + l, agg);
    k_node_upd<<<nblk_node, 256, 0, stream>>>(agg,
        wt + 7 * KP * KP, b_n2a + bo,
        wt + 8 * KP * KP, b_n2b + bo, x, n_eps + l);
  }
}